// Round 7
// baseline (253.537 us; speedup 1.0000x reference)
//
#include <hip/hip_runtime.h>
#include <hip/hip_fp16.h>
#include <stdint.h>

typedef __attribute__((ext_vector_type(8))) _Float16 f16x8;
typedef __attribute__((ext_vector_type(4))) float f32x4;

#define NIMG 40      // B*T
#define TFR  5
#define CIN  3
#define HH   64
#define WW   64
#define HW   4096
#define PPS  72      // LDS row stride for 64-wide front patch

union U32H2 { uint u; __half2 h; };

// ---------------- K0: weight prep (fp16) ----------------
// Wr_dcn[64][576]  kk = k*64+c          <- Wd[oc][c][k]
// Wr_om [32][576]  kk = k*64+c          <- Wom[oc][c][k] (rows 27..31 zero)
// Wr_f  [64][64]   kk = c*9+k (cur)     <- Wi[f][c][k]   (kk 27..63 zero)
// Wr_o  [64][64]   kk 0..26 cur, 27..53 ref <- Wo reordered (54..63 zero)
__global__ __launch_bounds__(256) void k_wprep(
    const float* __restrict__ Wd, const float* __restrict__ Wom,
    const float* __restrict__ Wi, const float* __restrict__ Wo,
    __half* __restrict__ Wr_dcn, __half* __restrict__ Wr_om,
    __half* __restrict__ Wr_f, __half* __restrict__ Wr_o)
{
  int idx = blockIdx.x*256 + threadIdx.x;
  if (idx < 36864) {                         // dcn
    int kk = idx % 576, oc = idx / 576;
    int k = kk >> 6, c = kk & 63;
    Wr_dcn[idx] = __float2half(Wd[oc*576 + c*9 + k]);
  } else if (idx < 36864 + 18432) {          // om
    int q = idx - 36864;
    int kk = q % 576, oc = q / 576;
    int k = kk >> 6, c = kk & 63;
    Wr_om[q] = (oc < 27) ? __float2half(Wom[oc*576 + c*9 + k]) : __float2half(0.f);
  } else if (idx < 36864 + 18432 + 4096) {   // front feat
    int q = idx - 36864 - 18432;
    int kk = q & 63, f = q >> 6;
    Wr_f[q] = (kk < 27) ? __float2half(Wi[f*27 + kk]) : __float2half(0.f);
  } else if (idx < 36864 + 18432 + 8192) {   // front off
    int q = idx - 36864 - 18432 - 4096;
    int kk = q & 63, f = q >> 6;
    float v = 0.f;
    if (kk < 27)       v = Wo[f*54 + 27 + kk];    // cur channels (concat idx 3..5)
    else if (kk < 54)  v = Wo[f*54 + (kk - 27)];  // ref channels (concat idx 0..2)
    Wr_o[q] = __float2half(v);
  }
}

// ---------------- K1: fused feat + off_feat via MFMA [NHWC fp16 out] ----------------
__global__ __launch_bounds__(256) void k_front(
    const float* __restrict__ x,
    const __half* __restrict__ Wr_f, const __half* __restrict__ Wr_o,
    const float* __restrict__ bi, const float* __restrict__ ai,
    const float* __restrict__ bo, const float* __restrict__ aof,
    __half* __restrict__ feat, __half* __restrict__ offf)
{
  __shared__ __align__(16) __half sp[32*PPS];
  int t = threadIdx.x, blk = blockIdx.x;
  int n = blk >> 7;
  int pbase = (blk & 127) * 32;
  int h = pbase >> 6;
  int wbase = pbase & 63;
  int n0 = (n/TFR)*TFR;
  const float* xc = x + (size_t)n*(CIN*HW);
  const float* xr = x + (size_t)n0*(CIN*HW);

  // im2col patch [32 px][64 kk]: kk 0..26 cur (c*9+k), 27..53 ref, 54..63 zero
  #pragma unroll
  for (int i = 0; i < 8; ++i) {
    int e = i*256 + t;
    int kk = e >> 5, px = e & 31;
    float v = 0.f;
    if (kk < 54) {
      int cur = (kk < 27);
      int kb = cur ? kk : kk - 27;
      int c = kb / 9, k = kb - c*9;
      int y  = h + k/3 - 1;
      int xx = wbase + px + (k - (k/3)*3) - 1;
      if (y >= 0 && y < HH && xx >= 0 && xx < WW)
        v = (cur ? xc : xr)[c*HW + y*WW + xx];
    }
    sp[px*PPS + kk] = __float2half(v);
  }
  __syncthreads();

  int wv = t >> 6, lane = t & 63;
  int row = lane & 15, ks = lane >> 4;
  const __half* af = Wr_f + (wv*16 + row)*64 + ks*8;
  const __half* aw = Wr_o + (wv*16 + row)*64 + ks*8;
  f16x8 af0 = *(const f16x8*)(af);
  f16x8 aw0 = *(const f16x8*)(aw);
  f16x8 aw1 = *(const f16x8*)(aw + 32);
  #pragma unroll
  for (int nt = 0; nt < 2; ++nt) {
    const __half* bp = sp + (nt*16 + row)*PPS + ks*8;
    f16x8 b0 = *(const f16x8*)(bp);
    f16x8 b1 = *(const f16x8*)(bp + 32);
    f32x4 accf = {0.f,0.f,0.f,0.f}, acco = {0.f,0.f,0.f,0.f};
    accf = __builtin_amdgcn_mfma_f32_16x16x32_f16(af0, b0, accf, 0, 0, 0);
    acco = __builtin_amdgcn_mfma_f32_16x16x32_f16(aw0, b0, acco, 0, 0, 0);
    acco = __builtin_amdgcn_mfma_f32_16x16x32_f16(aw1, b1, acco, 0, 0, 0);
    int p  = pbase + nt*16 + row;
    int f0 = wv*16 + ks*4;
    size_t base = ((size_t)n*HW + p)*64 + f0;
    union { ushort4 u; __half b[4]; } pf, po;
    #pragma unroll
    for (int j = 0; j < 4; ++j) {
      float vf = accf[j] + bi[f0+j];
      float aF = ai[f0+j];
      vf = vf >= 0.f ? vf : aF*vf;
      pf.b[j] = __float2half(vf);
      float vo = acco[j] + bo[f0+j];
      float aO = aof[f0+j];
      vo = vo >= 0.f ? vo : aO*vo;
      po.b[j] = __float2half(vo);
    }
    *(ushort4*)(feat + base) = pf.u;
    *(ushort4*)(offf + base) = po.u;
  }
}

// ---------------- K2: fused om-head + DCN, register-direct gather, barrier-free taps ----------------
// Block = one image row (64 px), 4 waves; wave g owns px g*16..g*16+15, computes all 64 oc.
__global__ __launch_bounds__(256) void k_dcn(
    const __half* __restrict__ feat, const __half* __restrict__ offf,
    const __half* __restrict__ Wr_dcn, const __half* __restrict__ Wr_om,
    const float* __restrict__ bom, const float* __restrict__ bd,
    float* __restrict__ out)
{
  __shared__ float som[27*64];                   // om values for this row's 64 pixels
  __shared__ __align__(16) int4  soff[64*9];     // 4 corner byte offsets into feat[n]
  __shared__ __align__(16) uint4 swgt[64*9];     // 4 corner weights as broadcast half2

  int t = threadIdx.x;
  int blk = blockIdx.x;
  int work = (blk & 7)*320 + (blk >> 3);         // XCD-contiguous: 5 images per XCD
  int n = work >> 6;
  int hrow = work & 63;
  int wv = t >> 6, lane = t & 63;
  int row = lane & 15, ks = lane >> 4;
  int px = wv*16 + row;                          // pixel column this lane owns (B-frag row)

  const char* ob = (const char*)(offf + (size_t)n*(HW*64));
  const char* fb = (const char*)(feat + (size_t)n*(HW*64));

  // ---- step A: om head; B-frags gathered straight from offf in registers ----
  {
    f32x4 aco0 = {0.f,0.f,0.f,0.f}, aco1 = {0.f,0.f,0.f,0.f};
    #pragma unroll
    for (int tap = 0; tap < 9; ++tap) {
      int ky = tap/3, kx = tap - ky*3;
      int y = hrow + ky - 1;
      int xx = px + kx - 1;
      bool valid = ((unsigned)y < 64u) & ((unsigned)xx < 64u);
      int pbyte = ((y<<6) + xx) << 7;
      #pragma unroll
      for (int hf = 0; hf < 2; ++hf) {
        uint4 raw = make_uint4(0,0,0,0);
        if (valid) raw = *(const uint4*)(ob + pbyte + hf*64 + ks*16);
        f16x8 b = *(f16x8*)&raw;
        f16x8 a0 = *(const f16x8*)(Wr_om + row*576 + tap*64 + hf*32 + ks*8);
        f16x8 a1 = *(const f16x8*)(Wr_om + (16+row)*576 + tap*64 + hf*32 + ks*8);
        aco0 = __builtin_amdgcn_mfma_f32_16x16x32_f16(a0, b, aco0, 0, 0, 0);
        aco1 = __builtin_amdgcn_mfma_f32_16x16x32_f16(a1, b, aco1, 0, 0, 0);
      }
    }
    #pragma unroll
    for (int j = 0; j < 4; ++j) {
      int oc0 = ks*4 + j;                        // 0..15: offsets, no sigmoid
      som[oc0*64 + px] = aco0[j] + bom[oc0];
      int oc1 = 16 + ks*4 + j;                   // 16..31: 16..17 offsets, 18..26 mask
      if (oc1 < 27) {
        float r = aco1[j] + bom[oc1];
        if (oc1 >= 18) r = 1.f/(1.f + __expf(-r));
        som[oc1*64 + px] = r;
      }
    }
  }
  __syncthreads();

  // ---- step B: per (pixel, tap) bilinear params from som ----
  for (int e = t; e < 64*9; e += 256) {
    int p9 = e / 9, k = e - p9*9;
    float dy = som[(2*k)*64 + p9];
    float dx = som[(2*k+1)*64 + p9];
    float m  = som[(18+k)*64 + p9];
    float py = (float)(hrow + (k/3) - 1) + dy;
    float qx = (float)(p9 + (k - (k/3)*3) - 1) + dx;
    float y0f = floorf(py), x0f = floorf(qx);
    float wy = py - y0f, wx = qx - x0f;
    int y0 = (int)y0f, x0 = (int)x0f;
    int y1 = y0 + 1, x1 = x0 + 1;
    float w00 = (1.f-wy)*(1.f-wx)*m;
    float w01 = (1.f-wy)*wx*m;
    float w10 = wy*(1.f-wx)*m;
    float w11 = wy*wx*m;
    if (y0 < 0 || y0 >= HH) { w00 = 0.f; w01 = 0.f; }
    if (y1 < 0 || y1 >= HH) { w10 = 0.f; w11 = 0.f; }
    if (x0 < 0 || x0 >= WW) { w00 = 0.f; w10 = 0.f; }
    if (x1 < 0 || x1 >= WW) { w01 = 0.f; w11 = 0.f; }
    int y0c = min(max(y0,0),HH-1), y1c = min(max(y1,0),HH-1);
    int x0c = min(max(x0,0),WW-1), x1c = min(max(x1,0),WW-1);
    soff[e] = make_int4((((y0c<<6)+x0c)<<7), (((y0c<<6)+x1c)<<7),
                        (((y1c<<6)+x0c)<<7), (((y1c<<6)+x1c)<<7));
    U32H2 u00, u01, u10, u11;
    u00.h = __float2half2_rn(w00); u01.h = __float2half2_rn(w01);
    u10.h = __float2half2_rn(w10); u11.h = __float2half2_rn(w11);
    swgt[e] = make_uint4(u00.u, u01.u, u10.u, u11.u);
  }
  __syncthreads();

  // ---- step C: 9 independent taps, register-direct gather -> MFMA (no barriers) ----
  f32x4 acc0 = {0.f,0.f,0.f,0.f}, acc1 = {0.f,0.f,0.f,0.f};
  f32x4 acc2 = {0.f,0.f,0.f,0.f}, acc3 = {0.f,0.f,0.f,0.f};
  #pragma unroll
  for (int tap = 0; tap < 9; ++tap) {
    int e = px*9 + tap;
    int4  off = soff[e];
    uint4 wq  = swgt[e];
    U32H2 W00, W01, W10, W11;
    W00.u = wq.x; W01.u = wq.y; W10.u = wq.z; W11.u = wq.w;
    #pragma unroll
    for (int hf = 0; hf < 2; ++hf) {
      int cb = hf*64 + ks*16;
      uint4 c00 = *(const uint4*)(fb + off.x + cb);
      uint4 c01 = *(const uint4*)(fb + off.y + cb);
      uint4 c10 = *(const uint4*)(fb + off.z + cb);
      uint4 c11 = *(const uint4*)(fb + off.w + cb);
      uint4 r;
#define BILIN(comp) { U32H2 a0v,a1v,a2v,a3v,res;                                \
      a0v.u = c00.comp; a1v.u = c01.comp; a2v.u = c10.comp; a3v.u = c11.comp;   \
      __half2 v = __hmul2(W00.h, a0v.h); v = __hfma2(W01.h, a1v.h, v);          \
      v = __hfma2(W10.h, a2v.h, v);      v = __hfma2(W11.h, a3v.h, v);          \
      res.h = v; r.comp = res.u; }
      BILIN(x) BILIN(y) BILIN(z) BILIN(w)
#undef BILIN
      f16x8 b = *(f16x8*)&r;
      const __half* ap = Wr_dcn + row*576 + tap*64 + hf*32 + ks*8;
      f16x8 a0 = *(const f16x8*)(ap);
      f16x8 a1 = *(const f16x8*)(ap + 16*576);
      f16x8 a2 = *(const f16x8*)(ap + 32*576);
      f16x8 a3 = *(const f16x8*)(ap + 48*576);
      acc0 = __builtin_amdgcn_mfma_f32_16x16x32_f16(a0, b, acc0, 0, 0, 0);
      acc1 = __builtin_amdgcn_mfma_f32_16x16x32_f16(a1, b, acc1, 0, 0, 0);
      acc2 = __builtin_amdgcn_mfma_f32_16x16x32_f16(a2, b, acc2, 0, 0, 0);
      acc3 = __builtin_amdgcn_mfma_f32_16x16x32_f16(a3, b, acc3, 0, 0, 0);
    }
  }

  // ---- epilogue ----
  int p = (hrow<<6) + px;
  float* op = out + (size_t)n*(64*HW) + p;
  #pragma unroll
  for (int j = 0; j < 4; ++j) {
    int oc = ks*4 + j;
    op[(oc     )*HW] = acc0[j] + bd[oc];
    op[(oc + 16)*HW] = acc1[j] + bd[oc + 16];
    op[(oc + 32)*HW] = acc2[j] + bd[oc + 32];
    op[(oc + 48)*HW] = acc3[j] + bd[oc + 48];
  }
}

// ---------------- launcher ----------------
extern "C" void kernel_launch(void* const* d_in, const int* in_sizes, int n_in,
                              void* d_out, int out_size, void* d_ws, size_t ws_size,
                              hipStream_t stream)
{
  const float* x   = (const float*)d_in[0];
  // d_in[1] = flow (unused)
  const float* Wi  = (const float*)d_in[2];
  const float* bi  = (const float*)d_in[3];
  const float* ai  = (const float*)d_in[4];
  const float* Wo  = (const float*)d_in[5];
  const float* bo  = (const float*)d_in[6];
  const float* aof = (const float*)d_in[7];
  const float* Wom = (const float*)d_in[8];
  const float* bom = (const float*)d_in[9];
  const float* Wd  = (const float*)d_in[10];
  const float* bd  = (const float*)d_in[11];
  float* out = (float*)d_out;

  // workspace: feat NHWC fp16 | off_feat NHWC fp16 | Wr_dcn | Wr_om | Wr_f | Wr_o
  __half* feat   = (__half*)d_ws;
  __half* offf   = feat + (size_t)NIMG*HW*64;
  __half* Wr_dcn = offf + (size_t)NIMG*HW*64;
  __half* Wr_om  = Wr_dcn + 64*576;
  __half* Wr_f   = Wr_om + 32*576;
  __half* Wr_o   = Wr_f + 64*64;

  hipLaunchKernelGGL(k_wprep, dim3(248),         dim3(256), 0, stream,
                     Wd, Wom, Wi, Wo, Wr_dcn, Wr_om, Wr_f, Wr_o);
  hipLaunchKernelGGL(k_front, dim3(NIMG*HW/32),  dim3(256), 0, stream,
                     x, Wr_f, Wr_o, bi, ai, bo, aof, feat, offf);
  hipLaunchKernelGGL(k_dcn,   dim3(NIMG*64),     dim3(256), 0, stream,
                     feat, offf, Wr_dcn, Wr_om, bom, bd, out);
}

// Round 8
// 243.981 us; speedup vs baseline: 1.0392x; 1.0392x over previous
//
#include <hip/hip_runtime.h>
#include <hip/hip_fp16.h>
#include <stdint.h>

typedef __attribute__((ext_vector_type(8))) _Float16 f16x8;
typedef __attribute__((ext_vector_type(4))) float f32x4;

#define NIMG 40      // B*T
#define TFR  5
#define CIN  3
#define HH   64
#define WW   64
#define HW   4096
#define PPS  72      // LDS row stride for 64-wide front patch
#define CSTR 144     // staged-feat col stride in BYTES (128 data + 16 pad -> bank spread)

union U32H2 { uint u; __half2 h; };

// ---------------- K0: weight prep (fp16) ----------------
// Wr_dcn[64][576]  kk = k*64+c          <- Wd[oc][c][k]
// Wr_om [32][576]  kk = k*64+c          <- Wom[oc][c][k] (rows 27..31 zero)
// Wr_f  [64][64]   kk = c*9+k (cur)     <- Wi[f][c][k]   (kk 27..63 zero)
// Wr_o  [64][64]   kk 0..26 cur, 27..53 ref <- Wo reordered (54..63 zero)
__global__ __launch_bounds__(256) void k_wprep(
    const float* __restrict__ Wd, const float* __restrict__ Wom,
    const float* __restrict__ Wi, const float* __restrict__ Wo,
    __half* __restrict__ Wr_dcn, __half* __restrict__ Wr_om,
    __half* __restrict__ Wr_f, __half* __restrict__ Wr_o)
{
  int idx = blockIdx.x*256 + threadIdx.x;
  if (idx < 36864) {                         // dcn
    int kk = idx % 576, oc = idx / 576;
    int k = kk >> 6, c = kk & 63;
    Wr_dcn[idx] = __float2half(Wd[oc*576 + c*9 + k]);
  } else if (idx < 36864 + 18432) {          // om
    int q = idx - 36864;
    int kk = q % 576, oc = q / 576;
    int k = kk >> 6, c = kk & 63;
    Wr_om[q] = (oc < 27) ? __float2half(Wom[oc*576 + c*9 + k]) : __float2half(0.f);
  } else if (idx < 36864 + 18432 + 4096) {   // front feat
    int q = idx - 36864 - 18432;
    int kk = q & 63, f = q >> 6;
    Wr_f[q] = (kk < 27) ? __float2half(Wi[f*27 + kk]) : __float2half(0.f);
  } else if (idx < 36864 + 18432 + 8192) {   // front off
    int q = idx - 36864 - 18432 - 4096;
    int kk = q & 63, f = q >> 6;
    float v = 0.f;
    if (kk < 27)       v = Wo[f*54 + 27 + kk];    // cur channels (concat idx 3..5)
    else if (kk < 54)  v = Wo[f*54 + (kk - 27)];  // ref channels (concat idx 0..2)
    Wr_o[q] = __float2half(v);
  }
}

// ---------------- K1: fused feat + off_feat via MFMA [NHWC fp16 out] ----------------
__global__ __launch_bounds__(256) void k_front(
    const float* __restrict__ x,
    const __half* __restrict__ Wr_f, const __half* __restrict__ Wr_o,
    const float* __restrict__ bi, const float* __restrict__ ai,
    const float* __restrict__ bo, const float* __restrict__ aof,
    __half* __restrict__ feat, __half* __restrict__ offf)
{
  __shared__ __align__(16) __half sp[32*PPS];
  int t = threadIdx.x, blk = blockIdx.x;
  int n = blk >> 7;
  int pbase = (blk & 127) * 32;
  int h = pbase >> 6;
  int wbase = pbase & 63;
  int n0 = (n/TFR)*TFR;
  const float* xc = x + (size_t)n*(CIN*HW);
  const float* xr = x + (size_t)n0*(CIN*HW);

  // im2col patch [32 px][64 kk]: kk 0..26 cur (c*9+k), 27..53 ref, 54..63 zero
  #pragma unroll
  for (int i = 0; i < 8; ++i) {
    int e = i*256 + t;
    int kk = e >> 5, px = e & 31;
    float v = 0.f;
    if (kk < 54) {
      int cur = (kk < 27);
      int kb = cur ? kk : kk - 27;
      int c = kb / 9, k = kb - c*9;
      int y  = h + k/3 - 1;
      int xx = wbase + px + (k - (k/3)*3) - 1;
      if (y >= 0 && y < HH && xx >= 0 && xx < WW)
        v = (cur ? xc : xr)[c*HW + y*WW + xx];
    }
    sp[px*PPS + kk] = __float2half(v);
  }
  __syncthreads();

  int wv = t >> 6, lane = t & 63;
  int row = lane & 15, ks = lane >> 4;
  const __half* af = Wr_f + (wv*16 + row)*64 + ks*8;
  const __half* aw = Wr_o + (wv*16 + row)*64 + ks*8;
  f16x8 af0 = *(const f16x8*)(af);
  f16x8 aw0 = *(const f16x8*)(aw);
  f16x8 aw1 = *(const f16x8*)(aw + 32);
  #pragma unroll
  for (int nt = 0; nt < 2; ++nt) {
    const __half* bp = sp + (nt*16 + row)*PPS + ks*8;
    f16x8 b0 = *(const f16x8*)(bp);
    f16x8 b1 = *(const f16x8*)(bp + 32);
    f32x4 accf = {0.f,0.f,0.f,0.f}, acco = {0.f,0.f,0.f,0.f};
    accf = __builtin_amdgcn_mfma_f32_16x16x32_f16(af0, b0, accf, 0, 0, 0);
    acco = __builtin_amdgcn_mfma_f32_16x16x32_f16(aw0, b0, acco, 0, 0, 0);
    acco = __builtin_amdgcn_mfma_f32_16x16x32_f16(aw1, b1, acco, 0, 0, 0);
    int p  = pbase + nt*16 + row;
    int f0 = wv*16 + ks*4;
    size_t base = ((size_t)n*HW + p)*64 + f0;
    union { ushort4 u; __half b[4]; } pf, po;
    #pragma unroll
    for (int j = 0; j < 4; ++j) {
      float vf = accf[j] + bi[f0+j];
      float aF = ai[f0+j];
      vf = vf >= 0.f ? vf : aF*vf;
      pf.b[j] = __float2half(vf);
      float vo = acco[j] + bo[f0+j];
      float aO = aof[f0+j];
      vo = vo >= 0.f ? vo : aO*vo;
      po.b[j] = __float2half(vo);
    }
    *(ushort4*)(feat + base) = pf.u;
    *(ushort4*)(offf + base) = po.u;
  }
}

// ---------------- K2: fused om-head + DCN, LDS-staged gather ----------------
// Block = 32 px (half row). feat neighborhood rows h-2..h+2, cols wbase-2..wbase+33
// staged in LDS; bilinear corners read from LDS (global fallback when |offset|>=1).
__global__ __launch_bounds__(256) void k_dcn(
    const __half* __restrict__ feat, const __half* __restrict__ offf,
    const __half* __restrict__ Wr_dcn, const __half* __restrict__ Wr_om,
    const float* __restrict__ bom, const float* __restrict__ bd,
    float* __restrict__ out)
{
  __shared__ __align__(16) char sfeat[5*36*CSTR];  // 25.3KB staged feat region
  __shared__ float som[27*32];                     // om values for this block's pixels
  __shared__ __align__(16) int4  soff[32*9];       // corner offs: >=0 LDS byte, <0 ~global byte
  __shared__ __align__(16) uint4 swgt[32*9];       // 4 corner weights as broadcast half2

  int t = threadIdx.x;
  int blk = blockIdx.x;
  int work = (blk & 7)*640 + (blk >> 3);           // XCD-contiguous: 5 images per XCD
  int n = work >> 7;
  int pbase = (work & 127) * 32;
  int hrow = pbase >> 6, wbase = pbase & 63;
  int wv = t >> 6, lane = t & 63;
  int row = lane & 15, ks = lane >> 4;

  const char* ob = (const char*)(offf + (size_t)n*(HW*64));
  const char* fb = (const char*)(feat + (size_t)n*(HW*64));

  int rlo = max(0, hrow-2), rhi = min(63, hrow+2);
  int clo = max(0, wbase-2), chi = min(63, wbase+33);
  int nrows = rhi - rlo + 1, ncols = chi - clo + 1;

  // ---- step 0: stage feat region into LDS ----
  {
    int units = nrows*ncols*8;                     // uint4 units
    int den = ncols*8;
    for (int u = t; u < units; u += 256) {
      int r = u / den;
      int rem = u - r*den;
      int ci = rem >> 3, q = rem & 7;
      int y = rlo + r, xx = clo + ci;
      uint4 v = *(const uint4*)(fb + (((y<<6)+xx)<<7) + q*16);
      *(uint4*)(sfeat + (r*36 + ci)*CSTR + q*16) = v;
    }
  }

  // ---- step 1: om head; B-frags gathered straight from offf in registers ----
  {
    int mt = wv >> 1, nt = wv & 1;
    int pxl = nt*16 + row;
    int w = wbase + pxl;
    f32x4 acc = {0.f,0.f,0.f,0.f};
    #pragma unroll
    for (int tap = 0; tap < 9; ++tap) {
      int ky = tap/3, kx = tap - ky*3;
      int y = hrow + ky - 1;
      int xx = w + kx - 1;
      bool valid = ((unsigned)y < 64u) & ((unsigned)xx < 64u);
      int pbyte = ((y<<6) + xx) << 7;
      #pragma unroll
      for (int hf = 0; hf < 2; ++hf) {
        uint4 raw = make_uint4(0,0,0,0);
        if (valid) raw = *(const uint4*)(ob + pbyte + hf*64 + ks*16);
        f16x8 b = *(f16x8*)&raw;
        f16x8 a = *(const f16x8*)(Wr_om + (mt*16 + row)*576 + tap*64 + hf*32 + ks*8);
        acc = __builtin_amdgcn_mfma_f32_16x16x32_f16(a, b, acc, 0, 0, 0);
      }
    }
    #pragma unroll
    for (int j = 0; j < 4; ++j) {
      int oc = mt*16 + ks*4 + j;
      if (oc < 27) {
        float r = acc[j] + bom[oc];
        if (oc >= 18) r = 1.f/(1.f + __expf(-r));
        som[oc*32 + pxl] = r;
      }
    }
  }
  __syncthreads();

  // ---- step 2: per (pixel, tap) bilinear params from som; encode LDS/global offs ----
  for (int e = t; e < 32*9; e += 256) {
    int px = e / 9, k = e - px*9;
    int p = pbase + px;
    int hh = p >> 6, w = p & 63;
    float dy = som[(2*k)*32 + px];
    float dx = som[(2*k+1)*32 + px];
    float m  = som[(18+k)*32 + px];
    float py = (float)(hh + (k/3) - 1) + dy;
    float qx = (float)(w + (k - (k/3)*3) - 1) + dx;
    float y0f = floorf(py), x0f = floorf(qx);
    float wy = py - y0f, wx = qx - x0f;
    int y0 = (int)y0f, x0 = (int)x0f;
    int y1 = y0 + 1, x1 = x0 + 1;
    float w00 = (1.f-wy)*(1.f-wx)*m;
    float w01 = (1.f-wy)*wx*m;
    float w10 = wy*(1.f-wx)*m;
    float w11 = wy*wx*m;
    if (y0 < 0 || y0 >= HH) { w00 = 0.f; w01 = 0.f; }
    if (y1 < 0 || y1 >= HH) { w10 = 0.f; w11 = 0.f; }
    if (x0 < 0 || x0 >= WW) { w00 = 0.f; w10 = 0.f; }
    if (x1 < 0 || x1 >= WW) { w01 = 0.f; w11 = 0.f; }
    int y0c = min(max(y0,0),HH-1), y1c = min(max(y1,0),HH-1);
    int x0c = min(max(x0,0),WW-1), x1c = min(max(x1,0),WW-1);
    int yr0 = y0c - rlo, yr1 = y1c - rlo;
    int xr0 = x0c - clo, xr1 = x1c - clo;
    bool i00 = ((unsigned)yr0 < (unsigned)nrows) & ((unsigned)xr0 < (unsigned)ncols);
    bool i01 = ((unsigned)yr0 < (unsigned)nrows) & ((unsigned)xr1 < (unsigned)ncols);
    bool i10 = ((unsigned)yr1 < (unsigned)nrows) & ((unsigned)xr0 < (unsigned)ncols);
    bool i11 = ((unsigned)yr1 < (unsigned)nrows) & ((unsigned)xr1 < (unsigned)ncols);
    int e00 = i00 ? (yr0*36 + xr0)*CSTR : ~(((y0c<<6)+x0c)<<7);
    int e01 = i01 ? (yr0*36 + xr1)*CSTR : ~(((y0c<<6)+x1c)<<7);
    int e10 = i10 ? (yr1*36 + xr0)*CSTR : ~(((y1c<<6)+x0c)<<7);
    int e11 = i11 ? (yr1*36 + xr1)*CSTR : ~(((y1c<<6)+x1c)<<7);
    soff[e] = make_int4(e00, e01, e10, e11);
    U32H2 u00, u01, u10, u11;
    u00.h = __float2half2_rn(w00); u01.h = __float2half2_rn(w01);
    u10.h = __float2half2_rn(w10); u11.h = __float2half2_rn(w11);
    swgt[e] = make_uint4(u00.u, u01.u, u10.u, u11.u);
  }
  __syncthreads();

  // ---- step 3: 9 taps, LDS gather -> MFMA B-frags in registers ----
  int nt = wv & 1, mt0 = wv >> 1;
  int pxl = nt*16 + row;
  f32x4 acc0 = {0.f,0.f,0.f,0.f}, acc1 = {0.f,0.f,0.f,0.f};
  #pragma unroll
  for (int tap = 0; tap < 9; ++tap) {
    int e = pxl*9 + tap;
    int4  off = soff[e];
    uint4 wq  = swgt[e];
    U32H2 W00, W01, W10, W11;
    W00.u = wq.x; W01.u = wq.y; W10.u = wq.z; W11.u = wq.w;
    #pragma unroll
    for (int hf = 0; hf < 2; ++hf) {
      int cb = hf*64 + ks*16;
      uint4 c00, c01, c10, c11;
      if (off.x >= 0) c00 = *(const uint4*)(sfeat + off.x + cb);
      else            c00 = *(const uint4*)(fb + ~off.x + cb);
      if (off.y >= 0) c01 = *(const uint4*)(sfeat + off.y + cb);
      else            c01 = *(const uint4*)(fb + ~off.y + cb);
      if (off.z >= 0) c10 = *(const uint4*)(sfeat + off.z + cb);
      else            c10 = *(const uint4*)(fb + ~off.z + cb);
      if (off.w >= 0) c11 = *(const uint4*)(sfeat + off.w + cb);
      else            c11 = *(const uint4*)(fb + ~off.w + cb);
      uint4 r;
#define BILIN(comp) { U32H2 a0v,a1v,a2v,a3v,res;                                \
      a0v.u = c00.comp; a1v.u = c01.comp; a2v.u = c10.comp; a3v.u = c11.comp;   \
      __half2 v = __hmul2(W00.h, a0v.h); v = __hfma2(W01.h, a1v.h, v);          \
      v = __hfma2(W10.h, a2v.h, v);      v = __hfma2(W11.h, a3v.h, v);          \
      res.h = v; r.comp = res.u; }
      BILIN(x) BILIN(y) BILIN(z) BILIN(w)
#undef BILIN
      f16x8 b = *(f16x8*)&r;
      const __half* ap = Wr_dcn + (mt0*16 + row)*576 + tap*64 + hf*32 + ks*8;
      f16x8 a0 = *(const f16x8*)(ap);
      f16x8 a1 = *(const f16x8*)(ap + 32*576);
      acc0 = __builtin_amdgcn_mfma_f32_16x16x32_f16(a0, b, acc0, 0, 0, 0);
      acc1 = __builtin_amdgcn_mfma_f32_16x16x32_f16(a1, b, acc1, 0, 0, 0);
    }
  }

  // ---- epilogue ----
  int p = pbase + pxl;
  float* op = out + (size_t)n*(64*HW) + p;
  #pragma unroll
  for (int j = 0; j < 4; ++j) {
    int oc0 = mt0*16 + ks*4 + j;
    int oc1 = (mt0+2)*16 + ks*4 + j;
    op[oc0*HW] = acc0[j] + bd[oc0];
    op[oc1*HW] = acc1[j] + bd[oc1];
  }
}

// ---------------- launcher ----------------
extern "C" void kernel_launch(void* const* d_in, const int* in_sizes, int n_in,
                              void* d_out, int out_size, void* d_ws, size_t ws_size,
                              hipStream_t stream)
{
  const float* x   = (const float*)d_in[0];
  // d_in[1] = flow (unused)
  const float* Wi  = (const float*)d_in[2];
  const float* bi  = (const float*)d_in[3];
  const float* ai  = (const float*)d_in[4];
  const float* Wo  = (const float*)d_in[5];
  const float* bo  = (const float*)d_in[6];
  const float* aof = (const float*)d_in[7];
  const float* Wom = (const float*)d_in[8];
  const float* bom = (const float*)d_in[9];
  const float* Wd  = (const float*)d_in[10];
  const float* bd  = (const float*)d_in[11];
  float* out = (float*)d_out;

  // workspace: feat NHWC fp16 | off_feat NHWC fp16 | Wr_dcn | Wr_om | Wr_f | Wr_o
  __half* feat   = (__half*)d_ws;
  __half* offf   = feat + (size_t)NIMG*HW*64;
  __half* Wr_dcn = offf + (size_t)NIMG*HW*64;
  __half* Wr_om  = Wr_dcn + 64*576;
  __half* Wr_f   = Wr_om + 32*576;
  __half* Wr_o   = Wr_f + 64*64;

  hipLaunchKernelGGL(k_wprep, dim3(248),         dim3(256), 0, stream,
                     Wd, Wom, Wi, Wo, Wr_dcn, Wr_om, Wr_f, Wr_o);
  hipLaunchKernelGGL(k_front, dim3(NIMG*HW/32),  dim3(256), 0, stream,
                     x, Wr_f, Wr_o, bi, ai, bo, aof, feat, offf);
  hipLaunchKernelGGL(k_dcn,   dim3(NIMG*HW/32),  dim3(256), 0, stream,
                     feat, offf, Wr_dcn, Wr_om, bom, bd, out);
}

// Round 9
// 180.295 us; speedup vs baseline: 1.4062x; 1.3532x over previous
//
#include <hip/hip_runtime.h>
#include <hip/hip_fp16.h>
#include <stdint.h>

typedef __attribute__((ext_vector_type(8))) _Float16 f16x8;
typedef __attribute__((ext_vector_type(4))) float f32x4;

#define NIMG 40      // B*T
#define TFR  5
#define CIN  3
#define HH   64
#define WW   64
#define HW   4096
#define PPS  72      // LDS row stride for 64-wide front patch
#define RSTR 72      // om region col stride (halves)
#define CSTR 144     // feat window col stride in BYTES (128 data + 16 pad)

union U32H2 { uint u; __half2 h; };

// ---------------- K0: weight prep (fp16) ----------------
__global__ __launch_bounds__(256) void k_wprep(
    const float* __restrict__ Wd, const float* __restrict__ Wom,
    const float* __restrict__ Wi, const float* __restrict__ Wo,
    __half* __restrict__ Wr_dcn, __half* __restrict__ Wr_om,
    __half* __restrict__ Wr_f, __half* __restrict__ Wr_o)
{
  int idx = blockIdx.x*256 + threadIdx.x;
  if (idx < 36864) {                         // dcn: [oc][k*64+c]
    int kk = idx % 576, oc = idx / 576;
    int k = kk >> 6, c = kk & 63;
    Wr_dcn[idx] = __float2half(Wd[oc*576 + c*9 + k]);
  } else if (idx < 36864 + 18432) {          // om
    int q = idx - 36864;
    int kk = q % 576, oc = q / 576;
    int k = kk >> 6, c = kk & 63;
    Wr_om[q] = (oc < 27) ? __float2half(Wom[oc*576 + c*9 + k]) : __float2half(0.f);
  } else if (idx < 36864 + 18432 + 4096) {   // front feat
    int q = idx - 36864 - 18432;
    int kk = q & 63, f = q >> 6;
    Wr_f[q] = (kk < 27) ? __float2half(Wi[f*27 + kk]) : __float2half(0.f);
  } else if (idx < 36864 + 18432 + 8192) {   // front off
    int q = idx - 36864 - 18432 - 4096;
    int kk = q & 63, f = q >> 6;
    float v = 0.f;
    if (kk < 27)       v = Wo[f*54 + 27 + kk];
    else if (kk < 54)  v = Wo[f*54 + (kk - 27)];
    Wr_o[q] = __float2half(v);
  }
}

// ---------------- K1: fused feat + off_feat via MFMA [NHWC fp16 out] ----------------
__global__ __launch_bounds__(256) void k_front(
    const float* __restrict__ x,
    const __half* __restrict__ Wr_f, const __half* __restrict__ Wr_o,
    const float* __restrict__ bi, const float* __restrict__ ai,
    const float* __restrict__ bo, const float* __restrict__ aof,
    __half* __restrict__ feat, __half* __restrict__ offf)
{
  __shared__ __align__(16) __half sp[32*PPS];
  int t = threadIdx.x, blk = blockIdx.x;
  int n = blk >> 7;
  int pbase = (blk & 127) * 32;
  int h = pbase >> 6;
  int wbase = pbase & 63;
  int n0 = (n/TFR)*TFR;
  const float* xc = x + (size_t)n*(CIN*HW);
  const float* xr = x + (size_t)n0*(CIN*HW);

  #pragma unroll
  for (int i = 0; i < 8; ++i) {
    int e = i*256 + t;
    int kk = e >> 5, px = e & 31;
    float v = 0.f;
    if (kk < 54) {
      int cur = (kk < 27);
      int kb = cur ? kk : kk - 27;
      int c = kb / 9, k = kb - c*9;
      int y  = h + k/3 - 1;
      int xx = wbase + px + (k - (k/3)*3) - 1;
      if (y >= 0 && y < HH && xx >= 0 && xx < WW)
        v = (cur ? xc : xr)[c*HW + y*WW + xx];
    }
    sp[px*PPS + kk] = __float2half(v);
  }
  __syncthreads();

  int wv = t >> 6, lane = t & 63;
  int row = lane & 15, ks = lane >> 4;
  const __half* af = Wr_f + (wv*16 + row)*64 + ks*8;
  const __half* aw = Wr_o + (wv*16 + row)*64 + ks*8;
  f16x8 af0 = *(const f16x8*)(af);
  f16x8 aw0 = *(const f16x8*)(aw);
  f16x8 aw1 = *(const f16x8*)(aw + 32);
  #pragma unroll
  for (int nt = 0; nt < 2; ++nt) {
    const __half* bp = sp + (nt*16 + row)*PPS + ks*8;
    f16x8 b0 = *(const f16x8*)(bp);
    f16x8 b1 = *(const f16x8*)(bp + 32);
    f32x4 accf = {0.f,0.f,0.f,0.f}, acco = {0.f,0.f,0.f,0.f};
    accf = __builtin_amdgcn_mfma_f32_16x16x32_f16(af0, b0, accf, 0, 0, 0);
    acco = __builtin_amdgcn_mfma_f32_16x16x32_f16(aw0, b0, acco, 0, 0, 0);
    acco = __builtin_amdgcn_mfma_f32_16x16x32_f16(aw1, b1, acco, 0, 0, 0);
    int p  = pbase + nt*16 + row;
    int f0 = wv*16 + ks*4;
    size_t base = ((size_t)n*HW + p)*64 + f0;
    union { ushort4 u; __half b[4]; } pf, po;
    #pragma unroll
    for (int j = 0; j < 4; ++j) {
      float vf = accf[j] + bi[f0+j];
      float aF = ai[f0+j];
      vf = vf >= 0.f ? vf : aF*vf;
      pf.b[j] = __float2half(vf);
      float vo = acco[j] + bo[f0+j];
      float aO = aof[f0+j];
      vo = vo >= 0.f ? vo : aO*vo;
      po.b[j] = __float2half(vo);
    }
    *(ushort4*)(feat + base) = pf.u;
    *(ushort4*)(offf + base) = po.u;
  }
}

// ---------------- K2: fused om-head + DCN, block-uniform LDS fast path ----------------
__global__ __launch_bounds__(256) void k_dcn(
    const __half* __restrict__ feat, const __half* __restrict__ offf,
    const __half* __restrict__ Wr_dcn, const __half* __restrict__ Wr_om,
    const float* __restrict__ bom, const float* __restrict__ bd,
    float* __restrict__ out)
{
  __shared__ __align__(16) char smem[5*36*CSTR];  // 25.9KB: om region, then feat window
  __shared__ float som[27*32];
  __shared__ __align__(16) int4  soff[32*9];      // window-relative LDS byte offsets
  __shared__ __align__(16) uint4 swgt[32*9];      // 4 corner weights as broadcast half2
  __shared__ int sflag;

  int t = threadIdx.x;
  int blk = blockIdx.x;
  int work = (blk & 7)*640 + (blk >> 3);          // XCD-contiguous: 5 images per XCD
  int n = work >> 7;
  int pbase = (work & 127) * 32;
  int hrow = pbase >> 6, wbase = pbase & 63;
  int wv = t >> 6, lane = t & 63;
  int row = lane & 15, ks = lane >> 4;

  const char* ob = (const char*)(offf + (size_t)n*(HW*64));
  const char* fb = (const char*)(feat + (size_t)n*(HW*64));
  __half* region = (__half*)smem;
  char* sfeat = smem;

  if (t == 0) sflag = 1;

  // ---- P0: stage off_feat region rows hrow-1..+1, cols wbase-1..+32 ----
  for (int u = t; u < 816; u += 256) {            // 3*34*8 uint4 units
    int ry = u / 272;
    int rem = u - ry*272;
    int rx = rem >> 3, q = rem & 7;
    int y = hrow + ry - 1, xx = wbase + rx - 1;
    uint4 v = make_uint4(0,0,0,0);
    if ((unsigned)y < 64u && (unsigned)xx < 64u)
      v = *(const uint4*)(ob + (((y<<6)+xx)<<7) + q*16);
    *(uint4*)((char*)region + ((ry*34 + rx)*RSTR + q*8)*2) = v;
  }
  __syncthreads();

  // ---- P1: om head via MFMA from region ----
  {
    int mt = wv >> 1, nt = wv & 1;
    int pxl = nt*16 + row;
    f32x4 acc = {0.f,0.f,0.f,0.f};
    const __half* ap = Wr_om + (mt*16 + row)*576 + ks*8;
    #pragma unroll
    for (int k0 = 0; k0 < 18; ++k0) {
      int k = k0 >> 1, ky = k/3, kx = k - ky*3;
      int c0 = (k0 & 1)*32;
      f16x8 a = *(const f16x8*)(ap + k0*32);
      f16x8 b = *(const f16x8*)(region + (ky*34 + pxl + kx)*RSTR + c0 + ks*8);
      acc = __builtin_amdgcn_mfma_f32_16x16x32_f16(a, b, acc, 0, 0, 0);
    }
    #pragma unroll
    for (int j = 0; j < 4; ++j) {
      int oc = mt*16 + ks*4 + j;
      if (oc < 27) {
        float r = acc[j] + bom[oc];
        if (oc >= 18) r = 1.f/(1.f + __expf(-r));
        som[oc*32 + pxl] = r;
      }
    }
  }
  __syncthreads();

  // ---- P2: params -> soff/swgt (window-relative) + block flag ----
  for (int e = t; e < 32*9; e += 256) {
    int px = e / 9, k = e - px*9;
    int w = wbase + px;
    float dy = som[(2*k)*32 + px];
    float dx = som[(2*k+1)*32 + px];
    float m  = som[(18+k)*32 + px];
    float py = (float)(hrow + (k/3) - 1) + dy;
    float qx = (float)(w + (k - (k/3)*3) - 1) + dx;
    float y0f = floorf(py), x0f = floorf(qx);
    float wy = py - y0f, wx = qx - x0f;
    int y0 = (int)y0f, x0 = (int)x0f;
    int y1 = y0 + 1, x1 = x0 + 1;
    float w00 = (1.f-wy)*(1.f-wx)*m;
    float w01 = (1.f-wy)*wx*m;
    float w10 = wy*(1.f-wx)*m;
    float w11 = wy*wx*m;
    if (y0 < 0 || y0 >= HH) { w00 = 0.f; w01 = 0.f; }
    if (y1 < 0 || y1 >= HH) { w10 = 0.f; w11 = 0.f; }
    if (x0 < 0 || x0 >= WW) { w00 = 0.f; w10 = 0.f; }
    if (x1 < 0 || x1 >= WW) { w01 = 0.f; w11 = 0.f; }
    int y0c = min(max(y0,0),HH-1), y1c = min(max(y1,0),HH-1);
    int x0c = min(max(x0,0),WW-1), x1c = min(max(x1,0),WW-1);
    int yw0 = y0c - (hrow-2), yw1 = y1c - (hrow-2);
    int xw0 = x0c - (wbase-2), xw1 = x1c - (wbase-2);
    bool ok = ((unsigned)yw0 < 5u) & ((unsigned)yw1 < 5u)
            & ((unsigned)xw0 < 36u) & ((unsigned)xw1 < 36u);
    if (!ok) atomicAnd(&sflag, 0);
    int cy0 = min(max(yw0,0),4), cy1 = min(max(yw1,0),4);
    int cx0 = min(max(xw0,0),35), cx1 = min(max(xw1,0),35);
    soff[e] = make_int4((cy0*36 + cx0)*CSTR, (cy0*36 + cx1)*CSTR,
                        (cy1*36 + cx0)*CSTR, (cy1*36 + cx1)*CSTR);
    U32H2 u00, u01, u10, u11;
    u00.h = __float2half2_rn(w00); u01.h = __float2half2_rn(w01);
    u10.h = __float2half2_rn(w10); u11.h = __float2half2_rn(w11);
    swgt[e] = make_uint4(u00.u, u01.u, u10.u, u11.u);
  }

  // ---- P3: stage feat window rows hrow-2..+2, cols wbase-2..+33 (zero-filled) ----
  for (int u = t; u < 1440; u += 256) {           // 5*36*8 uint4 units
    int r = u / 288;
    int rem = u - r*288;
    int ci = rem >> 3, q = rem & 7;
    int y = hrow - 2 + r, xx = wbase - 2 + ci;
    uint4 v = make_uint4(0,0,0,0);
    if ((unsigned)y < 64u && (unsigned)xx < 64u)
      v = *(const uint4*)(fb + (((y<<6)+xx)<<7) + q*16);
    *(uint4*)(sfeat + (r*36 + ci)*CSTR + q*16) = v;
  }
  __syncthreads();

  // ---- P4: 9 taps, gather -> MFMA ----
  int nt = wv & 1, mt0 = wv >> 1;
  int pxl = nt*16 + row;
  f32x4 acc0 = {0.f,0.f,0.f,0.f}, acc1 = {0.f,0.f,0.f,0.f};
  const __half* a0base = Wr_dcn + (mt0*16 + row)*576 + ks*8;
  const __half* a1base = a0base + 32*576;

  if (sflag) {
    // fast path: branch-free LDS gather
    #pragma unroll
    for (int tap = 0; tap < 9; ++tap) {
      int e = pxl*9 + tap;
      int4  off = soff[e];
      uint4 wq  = swgt[e];
      U32H2 W00, W01, W10, W11;
      W00.u = wq.x; W01.u = wq.y; W10.u = wq.z; W11.u = wq.w;
      #pragma unroll
      for (int hf = 0; hf < 2; ++hf) {
        int cb = hf*64 + ks*16;
        uint4 c00 = *(const uint4*)(sfeat + off.x + cb);
        uint4 c01 = *(const uint4*)(sfeat + off.y + cb);
        uint4 c10 = *(const uint4*)(sfeat + off.z + cb);
        uint4 c11 = *(const uint4*)(sfeat + off.w + cb);
        uint4 r;
#define BILIN(comp) { U32H2 a0v,a1v,a2v,a3v,res;                                \
        a0v.u = c00.comp; a1v.u = c01.comp; a2v.u = c10.comp; a3v.u = c11.comp; \
        __half2 v = __hmul2(W00.h, a0v.h); v = __hfma2(W01.h, a1v.h, v);        \
        v = __hfma2(W10.h, a2v.h, v);      v = __hfma2(W11.h, a3v.h, v);        \
        res.h = v; r.comp = res.u; }
        BILIN(x) BILIN(y) BILIN(z) BILIN(w)
        f16x8 b = *(f16x8*)&r;
        f16x8 a0 = *(const f16x8*)(a0base + tap*64 + hf*32);
        f16x8 a1 = *(const f16x8*)(a1base + tap*64 + hf*32);
        acc0 = __builtin_amdgcn_mfma_f32_16x16x32_f16(a0, b, acc0, 0, 0, 0);
        acc1 = __builtin_amdgcn_mfma_f32_16x16x32_f16(a1, b, acc1, 0, 0, 0);
      }
    }
  } else {
    // slow path (rare): per-lane recompute, clamped global gather, branch-free
    #pragma unroll 1
    for (int tap = 0; tap < 9; ++tap) {
      float dy = som[(2*tap)*32 + pxl];
      float dx = som[(2*tap+1)*32 + pxl];
      float m  = som[(18+tap)*32 + pxl];
      int ky = tap/3, kx = tap - ky*3;
      float py = (float)(hrow + ky - 1) + dy;
      float qx = (float)(wbase + pxl + kx - 1) + dx;
      float y0f = floorf(py), x0f = floorf(qx);
      float wy = py - y0f, wx = qx - x0f;
      int y0 = (int)y0f, x0 = (int)x0f;
      int y1 = y0 + 1, x1 = x0 + 1;
      float w00 = (1.f-wy)*(1.f-wx)*m;
      float w01 = (1.f-wy)*wx*m;
      float w10 = wy*(1.f-wx)*m;
      float w11 = wy*wx*m;
      if (y0 < 0 || y0 >= HH) { w00 = 0.f; w01 = 0.f; }
      if (y1 < 0 || y1 >= HH) { w10 = 0.f; w11 = 0.f; }
      if (x0 < 0 || x0 >= WW) { w00 = 0.f; w10 = 0.f; }
      if (x1 < 0 || x1 >= WW) { w01 = 0.f; w11 = 0.f; }
      int y0c = min(max(y0,0),HH-1), y1c = min(max(y1,0),HH-1);
      int x0c = min(max(x0,0),WW-1), x1c = min(max(x1,0),WW-1);
      int o00 = (((y0c<<6)+x0c)<<7), o01 = (((y0c<<6)+x1c)<<7);
      int o10 = (((y1c<<6)+x0c)<<7), o11 = (((y1c<<6)+x1c)<<7);
      U32H2 W00, W01, W10, W11;
      W00.h = __float2half2_rn(w00); W01.h = __float2half2_rn(w01);
      W10.h = __float2half2_rn(w10); W11.h = __float2half2_rn(w11);
      #pragma unroll
      for (int hf = 0; hf < 2; ++hf) {
        int cb = hf*64 + ks*16;
        uint4 c00 = *(const uint4*)(fb + o00 + cb);
        uint4 c01 = *(const uint4*)(fb + o01 + cb);
        uint4 c10 = *(const uint4*)(fb + o10 + cb);
        uint4 c11 = *(const uint4*)(fb + o11 + cb);
        uint4 r;
        BILIN(x) BILIN(y) BILIN(z) BILIN(w)
#undef BILIN
        f16x8 b = *(f16x8*)&r;
        f16x8 a0 = *(const f16x8*)(a0base + tap*64 + hf*32);
        f16x8 a1 = *(const f16x8*)(a1base + tap*64 + hf*32);
        acc0 = __builtin_amdgcn_mfma_f32_16x16x32_f16(a0, b, acc0, 0, 0, 0);
        acc1 = __builtin_amdgcn_mfma_f32_16x16x32_f16(a1, b, acc1, 0, 0, 0);
      }
    }
  }

  // ---- epilogue ----
  int p = pbase + pxl;
  float* op = out + (size_t)n*(64*HW) + p;
  #pragma unroll
  for (int j = 0; j < 4; ++j) {
    int oc0 = mt0*16 + ks*4 + j;
    int oc1 = (mt0+2)*16 + ks*4 + j;
    op[oc0*HW] = acc0[j] + bd[oc0];
    op[oc1*HW] = acc1[j] + bd[oc1];
  }
}

// ---------------- launcher ----------------
extern "C" void kernel_launch(void* const* d_in, const int* in_sizes, int n_in,
                              void* d_out, int out_size, void* d_ws, size_t ws_size,
                              hipStream_t stream)
{
  const float* x   = (const float*)d_in[0];
  const float* Wi  = (const float*)d_in[2];
  const float* bi  = (const float*)d_in[3];
  const float* ai  = (const float*)d_in[4];
  const float* Wo  = (const float*)d_in[5];
  const float* bo  = (const float*)d_in[6];
  const float* aof = (const float*)d_in[7];
  const float* Wom = (const float*)d_in[8];
  const float* bom = (const float*)d_in[9];
  const float* Wd  = (const float*)d_in[10];
  const float* bd  = (const float*)d_in[11];
  float* out = (float*)d_out;

  __half* feat   = (__half*)d_ws;
  __half* offf   = feat + (size_t)NIMG*HW*64;
  __half* Wr_dcn = offf + (size_t)NIMG*HW*64;
  __half* Wr_om  = Wr_dcn + 64*576;
  __half* Wr_f   = Wr_om + 32*576;
  __half* Wr_o   = Wr_f + 64*64;

  hipLaunchKernelGGL(k_wprep, dim3(248),         dim3(256), 0, stream,
                     Wd, Wom, Wi, Wo, Wr_dcn, Wr_om, Wr_f, Wr_o);
  hipLaunchKernelGGL(k_front, dim3(NIMG*HW/32),  dim3(256), 0, stream,
                     x, Wr_f, Wr_o, bi, ai, bo, aof, feat, offf);
  hipLaunchKernelGGL(k_dcn,   dim3(NIMG*HW/32),  dim3(256), 0, stream,
                     feat, offf, Wr_dcn, Wr_om, bom, bd, out);
}